// Round 2
// baseline (293.821 us; speedup 1.0000x reference)
//
#include <hip/hip_runtime.h>

// Problem constants (fixed by setup_inputs in the reference)
#define BB 64      // batch
#define II 1024    // input dim
#define HH 4096    // hidden dim
#define OO 256     // output dim
#define EPSI 0.1f

// ---------------------------------------------------------------------------
// Kernel 1: W1 row norms. Grid = HH blocks.
//   nscaled[j] = -EPS * sum_i |W1[j,i]|
// ---------------------------------------------------------------------------
__global__ __launch_bounds__(256) void prep_kernel(
    const float* __restrict__ W1, float* __restrict__ nscaled) {
  const int bid = blockIdx.x;
  const int tid = threadIdx.x;
  __shared__ float red[4];

  const float4* row = (const float4*)(W1 + (size_t)bid * II);
  float4 v = row[tid];
  float s = fabsf(v.x) + fabsf(v.y) + fabsf(v.z) + fabsf(v.w);

#pragma unroll
  for (int off = 32; off > 0; off >>= 1) s += __shfl_down(s, off);
  if ((tid & 63) == 0) red[tid >> 6] = s;
  __syncthreads();
  if (tid == 0) nscaled[bid] = -EPSI * (red[0] + red[1] + red[2] + red[3]);
}

// ---------------------------------------------------------------------------
// Kernel 2: one block per output ROW r = b*OO + o. Grid = BB*OO = 16384.
// Consecutive blocks write consecutive 16 KB chunks -> the chip-wide store
// stream is LINEAR, exactly like the harness fill kernel that demonstrates
// 6.2-6.5 TB/s on this same buffer. (Previous BCHUNK=8 layout interleaved
// ~16K store streams at 4 MB stride -> suspected DRAM row thrash.)
//   pert[r, :] = y[r] * sign(W2[o,:]) * nscaled[:]
// W2 row re-read per block is L2-resident traffic (W2 = 4 MB/XCD-L2).
// Blocks r < OO (b == 0) also compute nn[b,o] = 4096*sum_j W2[o,j] + bias2[o]
// and broadcast it over the batch.
// ---------------------------------------------------------------------------
__global__ __launch_bounds__(256) void write_kernel(
    const int* __restrict__ y, const float* __restrict__ W2,
    const float* __restrict__ bias2, const float* __restrict__ nscaled,
    float* __restrict__ out) {
  const int r   = blockIdx.x;        // row index: r = b*OO + o
  const int o   = r & (OO - 1);
  const int tid = threadIdx.x;
  __shared__ float red[4];
  __shared__ float bval;

  const float4* w  = (const float4*)(W2 + (size_t)o * HH);
  const float4* ns = (const float4*)nscaled;
  const float yf = (float)y[r];      // block-uniform scalar load

  float* pert = out + (size_t)BB * OO;
  float4* dst = (float4*)(pert + (size_t)r * HH);

  float rsum = 0.0f;
#pragma unroll
  for (int k = 0; k < 4; ++k) {
    float4 wv = w[tid + 256 * k];
    float4 nv = ns[tid + 256 * k];
    rsum += wv.x + wv.y + wv.z + wv.w;   // cheap; only consumed when r < OO
    float4 p;
    p.x = yf * nv.x * ((wv.x > 0.f) ? 1.f : ((wv.x < 0.f) ? -1.f : 0.f));
    p.y = yf * nv.y * ((wv.y > 0.f) ? 1.f : ((wv.y < 0.f) ? -1.f : 0.f));
    p.z = yf * nv.z * ((wv.z > 0.f) ? 1.f : ((wv.z < 0.f) ? -1.f : 0.f));
    p.w = yf * nv.w * ((wv.w > 0.f) ? 1.f : ((wv.w < 0.f) ? -1.f : 0.f));
    dst[tid + 256 * k] = p;
  }

  // nn_output: blocks with b == 0 (r < OO, so o == r) own output column o.
  if (r < OO) {
#pragma unroll
    for (int off = 32; off > 0; off >>= 1) rsum += __shfl_down(rsum, off);
    if ((tid & 63) == 0) red[tid >> 6] = rsum;
    __syncthreads();
    if (tid == 0) bval = 4096.0f * (red[0] + red[1] + red[2] + red[3]) + bias2[o];
    __syncthreads();
    if (tid < BB) out[(size_t)tid * OO + o] = bval;
  }
}

extern "C" void kernel_launch(void* const* d_in, const int* in_sizes, int n_in,
                              void* d_out, int out_size, void* d_ws, size_t ws_size,
                              hipStream_t stream) {
  // setup_inputs order: x, y, W1, W2, bias1, bias2
  const int*   y     = (const int*)d_in[1];
  const float* W1    = (const float*)d_in[2];
  const float* W2    = (const float*)d_in[3];
  const float* bias2 = (const float*)d_in[5];
  float* out = (float*)d_out;

  float* nscaled = (float*)d_ws;  // HH floats

  prep_kernel<<<HH, 256, 0, stream>>>(W1, nscaled);
  write_kernel<<<BB * OO, 256, 0, stream>>>(y, W2, bias2, nscaled, out);
}